// Round 1
// baseline (387.311 us; speedup 1.0000x reference)
//
#include <hip/hip_runtime.h>

typedef _Float16 f16;
typedef __attribute__((ext_vector_type(8))) _Float16 half8;
typedef __attribute__((ext_vector_type(4))) _Float16 half4;
typedef __attribute__((ext_vector_type(4))) float f32x4;

#define S_LEN 4096
#define HID   768
#define NH    12
#define HD    64

// ---------------- convert hidden_states f32 -> f16 ----------------
__global__ __launch_bounds__(256) void k_convert_x(const float* __restrict__ x,
                                                   f16* __restrict__ xb) {
  int i = blockIdx.x * 256 + threadIdx.x;          // one float4 per thread
  float4 v = ((const float4*)x)[i];
  half4 h;
  h[0] = (f16)v.x; h[1] = (f16)v.y; h[2] = (f16)v.z; h[3] = (f16)v.w;
  *(half4*)&xb[(size_t)i * 4] = h;
}

// ---------------- transpose W [K,N] -> wt [N,K], f32 -> f16 ----------------
__global__ __launch_bounds__(256) void k_transw(const float* __restrict__ Wq,
                                                const float* __restrict__ Wk,
                                                const float* __restrict__ Wv,
                                                f16* __restrict__ wtb) {
  __shared__ float tile[32][33];
  const float* W = (blockIdx.z == 0) ? Wq : (blockIdx.z == 1 ? Wk : Wv);
  f16* wt = wtb + (size_t)blockIdx.z * HID * HID;
  int k0 = blockIdx.y * 32, n0 = blockIdx.x * 32;
  int tx = threadIdx.x, ty = threadIdx.y;
  #pragma unroll
  for (int j = ty; j < 32; j += 8)
    tile[j][tx] = W[(size_t)(k0 + j) * HID + n0 + tx];
  __syncthreads();
  #pragma unroll
  for (int j = ty; j < 32; j += 8)
    wt[(size_t)(n0 + j) * HID + k0 + tx] = (f16)tile[tx][j];
}

// ---------------- QKV projection GEMM (m97-style, 128x128 tile) ----------------
// C[s, o] = sum_k X[s,k] * W[k,o] + b[o]; wt is W^T in [N=768, K=768].
// z=0 -> Q [NH,S,HD]; z=1 -> K [NH,S,HD]; z=2 -> V^T [NH,HD,S]. All f16 out.
__global__ __launch_bounds__(256) void k_gemm_qkv(const f16* __restrict__ xb,
                                                  const f16* __restrict__ wtb,
                                                  const float* __restrict__ bq,
                                                  const float* __restrict__ bk,
                                                  const float* __restrict__ bv,
                                                  f16* __restrict__ qo,
                                                  f16* __restrict__ ko,
                                                  f16* __restrict__ vto) {
  __shared__ __align__(16) f16 As[128 * 32];   // 8 KB
  __shared__ __align__(16) f16 Bs[128 * 32];   // 8 KB
  const int z = blockIdx.z;
  const f16* wt = wtb + (size_t)z * HID * HID;
  const float* bias = (z == 0) ? bq : (z == 1 ? bk : bv);
  const int brow = blockIdx.y * 128;
  const int bcol = blockIdx.x * 128;
  const int tid = threadIdx.x, wid = tid >> 6, lane = tid & 63;
  const int wr = wid >> 1, wc = wid & 1;
  const int lrow = lane & 15, lk8 = (lane >> 4) * 8;
  const int srow = lane >> 2;          // staging row within 16-row group
  const int scol = (lane & 3) * 8;     // staging col (f16 elements)

  f32x4 acc[4][4] = {};

  for (int kt = 0; kt < HID; kt += 32) {
    // stage A and B tiles: 8 KB each via global_load_lds width 16
    #pragma unroll
    for (int r = 0; r < 2; r++) {
      int row = (wid * 2 + r) * 16 + srow;
      const f16* ga = xb + (size_t)(brow + row) * HID + kt + scol;
      const f16* gb = wt + (size_t)(bcol + row) * HID + kt + scol;
      __builtin_amdgcn_global_load_lds(
          (const __attribute__((address_space(1))) void*)ga,
          (__attribute__((address_space(3))) void*)(As + (wid * 2 + r) * 512),
          16, 0, 0);
      __builtin_amdgcn_global_load_lds(
          (const __attribute__((address_space(1))) void*)gb,
          (__attribute__((address_space(3))) void*)(Bs + (wid * 2 + r) * 512),
          16, 0, 0);
    }
    __syncthreads();

    half8 a[4], b[4];
    #pragma unroll
    for (int m = 0; m < 4; m++)
      a[m] = *(const half8*)&As[(wr * 64 + m * 16 + lrow) * 32 + lk8];
    #pragma unroll
    for (int n = 0; n < 4; n++)
      b[n] = *(const half8*)&Bs[(wc * 64 + n * 16 + lrow) * 32 + lk8];
    #pragma unroll
    for (int m = 0; m < 4; m++)
      #pragma unroll
      for (int n = 0; n < 4; n++)
        acc[m][n] = __builtin_amdgcn_mfma_f32_16x16x32_f16(a[m], b[n], acc[m][n], 0, 0, 0);
    __syncthreads();
  }

  // epilogue: bias add, f16 convert, scatter into head layouts
  #pragma unroll
  for (int m = 0; m < 4; m++) {
    int row0 = brow + wr * 64 + m * 16 + (lane >> 4) * 4;
    #pragma unroll
    for (int n = 0; n < 4; n++) {
      int col = bcol + wc * 64 + n * 16 + lrow;
      float bsv = bias[col];
      int h = col >> 6, d = col & 63;
      #pragma unroll
      for (int i = 0; i < 4; i++) {
        f16 v = (f16)(acc[m][n][i] + bsv);
        int r2 = row0 + i;
        if (z == 2)      vto[(size_t)(h * HD + d) * S_LEN + r2] = v;
        else if (z == 1) ko[((size_t)h * S_LEN + r2) * HD + d] = v;
        else             qo[((size_t)h * S_LEN + r2) * HD + d] = v;
      }
    }
  }
}

// ---------------- flash attention ----------------
// grid (64 q-blocks, 12 heads), 256 threads = 4 waves, wave owns 16 q rows.
// K/V fragments straight from global (L2-resident, 512KB/head each).
__global__ __launch_bounds__(256) void k_attn(const f16* __restrict__ qb,
                                              const f16* __restrict__ kb,
                                              const f16* __restrict__ vt,
                                              const float* __restrict__ mask,
                                              float* __restrict__ out) {
  __shared__ __align__(16) f16 P[4][16 * 72];   // per-wave P tile, stride 72 (2-way banks)
  const int h = blockIdx.y;
  const int tid = threadIdx.x, wid = tid >> 6, lane = tid & 63;
  const int lrow = lane & 15, lk8 = (lane >> 4) * 8;
  const int g4 = (lane >> 4) * 4;
  const int qrow0 = blockIdx.x * 64 + wid * 16;
  const size_t hqk = (size_t)h * S_LEN * HD;

  // Q fragments: A[m=q (lane&15)][k=hd] for the two K=32 chunks
  half8 aq[2];
  #pragma unroll
  for (int kk = 0; kk < 2; kk++)
    aq[kk] = *(const half8*)&qb[hqk + (size_t)(qrow0 + lrow) * HD + kk * 32 + lk8];

  f32x4 acc[4] = {};
  float mi[4] = {-INFINITY, -INFINITY, -INFINITY, -INFINITY};
  float li[4] = {0.f, 0.f, 0.f, 0.f};
  const float scale = 0.125f;   // 1/sqrt(64)

  for (int kt = 0; kt < S_LEN; kt += 64) {
    // ---- QK^T: S[16q x 64k] ----
    f32x4 s[4];
    #pragma unroll
    for (int nt = 0; nt < 4; nt++) {
      s[nt] = (f32x4){0.f, 0.f, 0.f, 0.f};
      const f16* kp = &kb[hqk + (size_t)(kt + nt * 16 + lrow) * HD + lk8];
      half8 b0 = *(const half8*)kp;
      half8 b1 = *(const half8*)(kp + 32);
      s[nt] = __builtin_amdgcn_mfma_f32_16x16x32_f16(aq[0], b0, s[nt], 0, 0, 0);
      s[nt] = __builtin_amdgcn_mfma_f32_16x16x32_f16(aq[1], b1, s[nt], 0, 0, 0);
    }
    // ---- online softmax (row = g4+i, col = nt*16+lrow) ----
    float p[4][4];
    #pragma unroll
    for (int nt = 0; nt < 4; nt++) {
      float mk = mask[kt + nt * 16 + lrow];
      #pragma unroll
      for (int i = 0; i < 4; i++) p[nt][i] = s[nt][i] * scale + mk;
    }
    float mx[4], rs[4], al[4];
    #pragma unroll
    for (int i = 0; i < 4; i++)
      mx[i] = fmaxf(fmaxf(p[0][i], p[1][i]), fmaxf(p[2][i], p[3][i]));
    #pragma unroll
    for (int off = 1; off < 16; off <<= 1)
      #pragma unroll
      for (int i = 0; i < 4; i++)
        mx[i] = fmaxf(mx[i], __shfl_xor(mx[i], off, 64));
    #pragma unroll
    for (int i = 0; i < 4; i++) {
      float mn = fmaxf(mi[i], mx[i]);
      al[i] = __expf(mi[i] - mn);
      mi[i] = mn;
    }
    #pragma unroll
    for (int nt = 0; nt < 4; nt++)
      #pragma unroll
      for (int i = 0; i < 4; i++) p[nt][i] = __expf(p[nt][i] - mi[i]);
    #pragma unroll
    for (int i = 0; i < 4; i++)
      rs[i] = (p[0][i] + p[1][i]) + (p[2][i] + p[3][i]);
    #pragma unroll
    for (int off = 1; off < 16; off <<= 1)
      #pragma unroll
      for (int i = 0; i < 4; i++)
        rs[i] += __shfl_xor(rs[i], off, 64);
    #pragma unroll
    for (int i = 0; i < 4; i++) li[i] = li[i] * al[i] + rs[i];
    #pragma unroll
    for (int nd = 0; nd < 4; nd++)
      #pragma unroll
      for (int i = 0; i < 4; i++) acc[nd][i] *= al[i];

    // ---- P -> LDS (C-layout write), re-read as A-fragments ----
    #pragma unroll
    for (int nt = 0; nt < 4; nt++)
      #pragma unroll
      for (int i = 0; i < 4; i++)
        P[wid][(g4 + i) * 72 + nt * 16 + lrow] = (f16)p[nt][i];

    // ---- PV: acc[16q x 64d] += P[16q x 64k] * V[64k x 64d] ----
    #pragma unroll
    for (int k2 = 0; k2 < 2; k2++) {
      half8 ap = *(const half8*)&P[wid][lrow * 72 + k2 * 32 + lk8];
      #pragma unroll
      for (int nd = 0; nd < 4; nd++) {
        const f16* vp = &vt[((size_t)h * HD + nd * 16 + lrow) * S_LEN + kt + k2 * 32 + lk8];
        half8 bvv = *(const half8*)vp;
        acc[nd] = __builtin_amdgcn_mfma_f32_16x16x32_f16(ap, bvv, acc[nd], 0, 0, 0);
      }
    }
  }

  // ---- epilogue: out[s, h*64+d] = acc / l ----
  #pragma unroll
  for (int nd = 0; nd < 4; nd++)
    #pragma unroll
    for (int i = 0; i < 4; i++) {
      int row = qrow0 + g4 + i;
      int d = nd * 16 + lrow;
      out[(size_t)row * HID + h * HD + d] = acc[nd][i] / li[i];
    }
}

extern "C" void kernel_launch(void* const* d_in, const int* in_sizes, int n_in,
                              void* d_out, int out_size, void* d_ws, size_t ws_size,
                              hipStream_t stream) {
  const float* x    = (const float*)d_in[0];
  const float* mask = (const float*)d_in[1];
  const float* Wq   = (const float*)d_in[2];
  const float* bq   = (const float*)d_in[3];
  const float* Wk   = (const float*)d_in[4];
  const float* bk   = (const float*)d_in[5];
  const float* Wv   = (const float*)d_in[6];
  const float* bv   = (const float*)d_in[7];
  float* out = (float*)d_out;

  char* ws = (char*)d_ws;
  f16* xb  = (f16*)(ws);                       // 4096*768*2       = 6291456 B
  f16* wtb = (f16*)(ws + 6291456);             // 3*768*768*2      = 3538944 B
  f16* qbb = (f16*)(ws + 9830400);             // 12*4096*64*2     = 6291456 B
  f16* kbb = (f16*)(ws + 16121856);            // 6291456 B
  f16* vtb = (f16*)(ws + 22413312);            // 6291456 B  (end 28704768)

  k_convert_x<<<dim3(3072), dim3(256), 0, stream>>>(x, xb);
  k_transw<<<dim3(24, 24, 3), dim3(32, 8), 0, stream>>>(Wq, Wk, Wv, wtb);
  k_gemm_qkv<<<dim3(6, 32, 3), dim3(256), 0, stream>>>(xb, wtb, bq, bk, bv, qbb, kbb, vtb);
  k_attn<<<dim3(64, 12), dim3(256), 0, stream>>>(qbb, kbb, vtb, mask, out);
}